// Round 14
// baseline (293.715 us; speedup 1.0000x reference)
//
#include <hip/hip_runtime.h>
#include <math.h>

#define NXR 8192
#define NCR 8192
#define HD  512
#define NSL 8            // attention j-slices (R11-proven)
#define JC  (NCR / NSL)  // 1024 cols per attention block
#define KSTR 520         // padded LDS col stride (elems)

typedef short s16x8 __attribute__((ext_vector_type(8)));
typedef float f32x4 __attribute__((ext_vector_type(4)));
typedef unsigned short u16;

struct P11 { const float* p[11]; };
struct P3  { const float* p[3]; };

__device__ inline u16 f2bf(float f) {
    unsigned int u = __float_as_uint(f);
    u = (u + 0x7FFFu + ((u >> 16) & 1u)) >> 16;
    return (u16)u;
}
__device__ inline float bf2f(u16 h) {
    return __uint_as_float(((unsigned int)h) << 16);
}

// ---------------------------------------------------------------------------
// Fused weight transpose + bf16 convert: out[z][n][k] = (bf16)in_z[k][n].
// ---------------------------------------------------------------------------
__global__ __launch_bounds__(256) void transpose_w_all(
    P11 srcs, u16* __restrict__ out)
{
    const float* in = srcs.p[blockIdx.z];
    u16* o = out + (size_t)blockIdx.z * HD * HD;
    __shared__ float tile[32][33];
    int bx = blockIdx.x * 32, by = blockIdx.y * 32;
    int tx = threadIdx.x & 31, ty = threadIdx.x >> 5;
    for (int r = ty; r < 32; r += 8)
        tile[r][tx] = in[(size_t)(by + r) * HD + bx + tx];
    __syncthreads();
    for (int r = ty; r < 32; r += 8)
        o[(size_t)(bx + r) * HD + by + tx] = f2bf(tile[tx][r]);
}

// ---------------------------------------------------------------------------
// Layer 0, 8 outputs/thread, bf16x8 store. grid (NXR*HD/2048, 1, nz)
// ---------------------------------------------------------------------------
__global__ __launch_bounds__(256) void layer0_all(
    const float* __restrict__ x, const float* __restrict__ c,
    P3 W0p, P3 b0p, u16* __restrict__ H, int net_base)
{
    int z = blockIdx.z;
    int net = net_base + z;
    const float* X  = (net == 0) ? x : c;
    const float* W0 = W0p.p[z];
    const float* b0 = b0p.p[z];
    u16* Hn = H + (size_t)z * NXR * HD;

    int idx = (blockIdx.x * 256 + threadIdx.x) * 8;
    int n = idx & (HD - 1);
    int row = idx >> 9;
    float x0 = X[row * 3 + 0], x1 = X[row * 3 + 1], x2 = X[row * 3 + 2];
    s16x8 o;
#pragma unroll
    for (int j = 0; j < 8; ++j) {
        float v = x0 * W0[n + j] + x1 * W0[HD + n + j] + x2 * W0[2 * HD + n + j] + b0[n + j];
        ((u16*)&o)[j] = f2bf(__sinf(v));
    }
    *(s16x8*)&Hn[idx] = o;
}

// ---------------------------------------------------------------------------
// GEMM v4 (A-in-registers, W-in-LDS, register-prefetch pipeline).
// Block = 128 rows x 128 cols (4 col-tiles); grid (64, 4, nets).
// ---------------------------------------------------------------------------
template<int ACT>
__global__ __launch_bounds__(256) void gemm_rs(
    const u16* __restrict__ Abase, const u16* __restrict__ Wt0, size_t wstride,
    P3 bias, u16* __restrict__ Cbase)
{
    __shared__ u16 Ws[32 * KSTR];   // 33,280 B

    const int net = blockIdx.z;
    const u16* A  = Abase + (size_t)net * NXR * HD;
    const u16* Wt = Wt0 + (size_t)net * wstride;
    const float* bias_p = bias.p[net];
    u16* C = Cbase + (size_t)net * NXR * HD;

    const int tid = threadIdx.x;
    const int wave = tid >> 6, lane = tid & 63;
    const int row0 = blockIdx.x * 128;
    const int colbase = blockIdx.y * 128;

    const int qm = lane & 15;
    const int g  = lane >> 4;

    // prefetch col-tile 0 into registers
    s16x8 pre[8];
#pragma unroll
    for (int i = 0; i < 8; ++i) {
        int chunk = i * 256 + tid;
        pre[i] = *(const s16x8*)(Wt + (size_t)(colbase + (chunk >> 6)) * HD + (chunk & 63) * 8);
    }

    // A fragments for this wave's 32 rows, all K
    s16x8 qf[16][2];
    {
        const u16* ap = A + (size_t)(row0 + wave * 32 + qm) * HD + g * 8;
#pragma unroll
        for (int t = 0; t < 16; ++t) {
            qf[t][0] = *(const s16x8*)(ap + t * 32);
            qf[t][1] = *(const s16x8*)(ap + (size_t)16 * HD + t * 32);
        }
    }

    for (int ct = 0; ct < 4; ++ct) {
        const int col0 = colbase + ct * 32;

        __syncthreads();
#pragma unroll
        for (int i = 0; i < 8; ++i) {
            int chunk = i * 256 + tid;
            *(s16x8*)&Ws[(chunk >> 6) * KSTR + (chunk & 63) * 8] = pre[i];
        }
        __syncthreads();

        if (ct + 1 < 4) {
            const int ncol = colbase + (ct + 1) * 32;
#pragma unroll
            for (int i = 0; i < 8; ++i) {
                int chunk = i * 256 + tid;
                pre[i] = *(const s16x8*)(Wt + (size_t)(ncol + (chunk >> 6)) * HD + (chunk & 63) * 8);
            }
        }

        f32x4 acc[2][2] = {};
#pragma unroll
        for (int kt = 0; kt < 16; ++kt) {
            s16x8 b0 = *(const s16x8*)&Ws[qm * KSTR + kt * 32 + g * 8];
            s16x8 b1 = *(const s16x8*)&Ws[(16 + qm) * KSTR + kt * 32 + g * 8];
            acc[0][0] = __builtin_amdgcn_mfma_f32_16x16x32_bf16(qf[kt][0], b0, acc[0][0], 0, 0, 0);
            acc[0][1] = __builtin_amdgcn_mfma_f32_16x16x32_bf16(qf[kt][0], b1, acc[0][1], 0, 0, 0);
            acc[1][0] = __builtin_amdgcn_mfma_f32_16x16x32_bf16(qf[kt][1], b0, acc[1][0], 0, 0, 0);
            acc[1][1] = __builtin_amdgcn_mfma_f32_16x16x32_bf16(qf[kt][1], b1, acc[1][1], 0, 0, 0);
        }

        float bv0 = bias_p[col0 + qm];
        float bv1 = bias_p[col0 + 16 + qm];
#pragma unroll
        for (int h = 0; h < 2; ++h) {
#pragma unroll
            for (int r = 0; r < 4; ++r) {
                int grow = row0 + wave * 32 + h * 16 + g * 4 + r;
                float v0 = acc[h][0][r] + bv0;
                float v1 = acc[h][1][r] + bv1;
                if (ACT) { v0 = __sinf(v0); v1 = __sinf(v1); }
                C[(size_t)grow * HD + col0 + qm]      = f2bf(v0);
                C[(size_t)grow * HD + col0 + 16 + qm] = f2bf(v1);
            }
        }
    }
}

// ---------------------------------------------------------------------------
// V output layer (M=3), one wave per row, fp32 out.
// ---------------------------------------------------------------------------
__global__ __launch_bounds__(256) void vout_k(
    const u16* __restrict__ H, const float* __restrict__ Wo,
    const float* __restrict__ bo, float* __restrict__ V)
{
    int wave = threadIdx.x >> 6, lane = threadIdx.x & 63;
    int row = blockIdx.x * 4 + wave;
    s16x8 hv = *(const s16x8*)(H + (size_t)row * HD + lane * 8);
    float a0 = 0, a1 = 0, a2 = 0;
#pragma unroll
    for (int j = 0; j < 8; ++j) {
        float hf = bf2f(((const u16*)&hv)[j]);
        int k = lane * 8 + j;
        a0 += hf * Wo[k * 3 + 0];
        a1 += hf * Wo[k * 3 + 1];
        a2 += hf * Wo[k * 3 + 2];
    }
#pragma unroll
    for (int d = 32; d >= 1; d >>= 1) {
        a0 += __shfl_down(a0, d);
        a1 += __shfl_down(a1, d);
        a2 += __shfl_down(a2, d);
    }
    if (lane == 0) {
        V[row * 3 + 0] = a0 + bo[0];
        V[row * 3 + 1] = a1 + bo[1];
        V[row * 3 + 2] = a2 + bo[2];
    }
}

// ---------------------------------------------------------------------------
// Fused attention (R11-exact): Q-in-registers (32 rows/wave), K-in-LDS.
// Block = 128 Q-rows x JC=1024 cols; grid (NSL=8, 64) = 512 blocks.
// kt loop: 2 ds_read_b128 feed 4 MFMAs, no barriers inside.
// ---------------------------------------------------------------------------
__global__ __launch_bounds__(256) void attn_mfma(
    const u16* __restrict__ Q, const u16* __restrict__ K,
    const float* __restrict__ V, float* __restrict__ out)
{
    __shared__ u16 Ks[32 * KSTR];   // 33,280 B

    const int tid = threadIdx.x;
    const int wave = tid >> 6, lane = tid & 63;
    const int row0 = blockIdx.y * 128;
    const int col_base = blockIdx.x * JC;

    const int qm = lane & 15;
    const int g  = lane >> 4;

    // Q fragments: 32 rows x all K = 32 x s16x8, loaded once.
    s16x8 qf[16][2];
    {
        const u16* qp = Q + (size_t)(row0 + wave * 32 + qm) * HD + g * 8;
#pragma unroll
        for (int t = 0; t < 16; ++t) {
            qf[t][0] = *(const s16x8*)(qp + t * 32);
            qf[t][1] = *(const s16x8*)(qp + (size_t)16 * HD + t * 32);
        }
    }

    float po[2][4][3] = {};

    for (int jt = 0; jt < JC / 32; ++jt) {
        const int col0 = col_base + jt * 32;

        // stage K tile [32 cols][512] into LDS
#pragma unroll
        for (int i = 0; i < 8; ++i) {
            int chunk = i * 256 + tid;
            int cc = chunk >> 6;
            int ch = chunk & 63;
            s16x8 v = *(const s16x8*)(K + (size_t)(col0 + cc) * HD + ch * 8);
            *(s16x8*)&Ks[cc * KSTR + ch * 8] = v;
        }
        __syncthreads();

        float vv[2][3];
#pragma unroll
        for (int ct = 0; ct < 2; ++ct) {
            size_t vr = (size_t)(col0 + ct * 16 + qm) * 3;
            vv[ct][0] = V[vr + 0];
            vv[ct][1] = V[vr + 1];
            vv[ct][2] = V[vr + 2];
        }

        f32x4 acc[2][2] = {};
#pragma unroll
        for (int kt = 0; kt < 16; ++kt) {
            s16x8 b0 = *(const s16x8*)&Ks[qm * KSTR + kt * 32 + g * 8];
            s16x8 b1 = *(const s16x8*)&Ks[(16 + qm) * KSTR + kt * 32 + g * 8];
            acc[0][0] = __builtin_amdgcn_mfma_f32_16x16x32_bf16(qf[kt][0], b0, acc[0][0], 0, 0, 0);
            acc[0][1] = __builtin_amdgcn_mfma_f32_16x16x32_bf16(qf[kt][0], b1, acc[0][1], 0, 0, 0);
            acc[1][0] = __builtin_amdgcn_mfma_f32_16x16x32_bf16(qf[kt][1], b0, acc[1][0], 0, 0, 0);
            acc[1][1] = __builtin_amdgcn_mfma_f32_16x16x32_bf16(qf[kt][1], b1, acc[1][1], 0, 0, 0);
        }

        // sigmoid + PV (rcp = v_rcp_f32, 1 ulp)
#pragma unroll
        for (int h = 0; h < 2; ++h)
#pragma unroll
            for (int ct = 0; ct < 2; ++ct)
#pragma unroll
                for (int r = 0; r < 4; ++r) {
                    float s = __builtin_amdgcn_rcpf(1.f + __expf(-acc[h][ct][r]));
                    po[h][r][0] += s * vv[ct][0];
                    po[h][r][1] += s * vv[ct][1];
                    po[h][r][2] += s * vv[ct][2];
                }
        __syncthreads();   // Ks reused next tile
    }

#pragma unroll
    for (int h = 0; h < 2; ++h)
#pragma unroll
        for (int r = 0; r < 4; ++r)
#pragma unroll
            for (int c = 0; c < 3; ++c) {
                float v = po[h][r][c];
                v += __shfl_down(v, 8, 16);
                v += __shfl_down(v, 4, 16);
                v += __shfl_down(v, 2, 16);
                v += __shfl_down(v, 1, 16);
                if (qm == 0)
                    atomicAdd(&out[(size_t)(row0 + wave * 32 + h * 16 + g * 4 + r) * 3 + c], v);
            }
}

// ---------------------------------------------------------------------------
// Workspace layouts (COMPACTED so the fused path engages at ~53.6 MB):
//  FUSED (needs >=53.7 MB): wT[0,5.5) | hA[5.5,29.5) | hB[29.5,53.5) | Vf
//  FALLBACK (38.1 MB):      wT[0,5.5) | R1[6,22) | R2[22,38) | Vf[38,..)
// ---------------------------------------------------------------------------
extern "C" void kernel_launch(void* const* d_in, const int* in_sizes, int n_in,
                              void* d_out, int out_size, void* d_ws, size_t ws_size,
                              hipStream_t stream)
{
    const float* x   = (const float*)d_in[0];
    const float* c   = (const float*)d_in[1];
    const float* QW0 = (const float*)d_in[2];
    const float* Qb0 = (const float*)d_in[3];
    const float* QWh = (const float*)d_in[4];
    const float* Qbh = (const float*)d_in[5];
    const float* QWo = (const float*)d_in[6];
    const float* Qbo = (const float*)d_in[7];
    const float* KW0 = (const float*)d_in[8];
    const float* Kb0 = (const float*)d_in[9];
    const float* KWh = (const float*)d_in[10];
    const float* Kbh = (const float*)d_in[11];
    const float* KWo = (const float*)d_in[12];
    const float* Kbo = (const float*)d_in[13];
    const float* VW0 = (const float*)d_in[14];
    const float* Vb0 = (const float*)d_in[15];
    const float* VWh = (const float*)d_in[16];
    const float* Vbh = (const float*)d_in[17];
    const float* VWo = (const float*)d_in[18];
    const float* Vbo = (const float*)d_in[19];

    char* ws = (char*)d_ws;
    const size_t WTN = (size_t)HD * HD;
    const size_t MB = 1048576;
    const size_t NET = (size_t)NXR * HD;

    // ---- weight transposes (1 dispatch, both paths) ----
    u16* wT = (u16*)ws;   // 11 * 512 KB bf16 = 5.5 MB
    P11 tsrc;
    for (int l = 0; l < 3; ++l) {
        tsrc.p[l * 3 + 0] = QWh + (size_t)l * WTN;
        tsrc.p[l * 3 + 1] = KWh + (size_t)l * WTN;
        tsrc.p[l * 3 + 2] = VWh + (size_t)l * WTN;
    }
    tsrc.p[9]  = QWo;
    tsrc.p[10] = KWo;
    transpose_w_all<<<dim3(16, 16, 11), 256, 0, stream>>>(tsrc, wT);

    const int L0G = NXR * HD / 2048;  // 2048
    const u16* Qb; const u16* Kb; const float* Vf;

    const size_t OFF_HA = 11 * WTN * sizeof(u16);          // 5,767,168
    const size_t OFF_HB = OFF_HA + 3 * NET * sizeof(u16);  // +24 MB
    const size_t OFF_VF = OFF_HB + 3 * NET * sizeof(u16);  // +24 MB
    const size_t FUSED_NEED = OFF_VF + (size_t)NCR * 3 * sizeof(float);  // ~53.6 MB

    if (ws_size >= FUSED_NEED) {
        // ================= fused path (9 dispatches) =================
        u16*   hA = (u16*)(ws + OFF_HA);
        u16*   hB = (u16*)(ws + OFF_HB);
        float* Vff = (float*)(ws + OFF_VF);

        P3 w0 = {{QW0, KW0, VW0}}, b0 = {{Qb0, Kb0, Vb0}};
        layer0_all<<<dim3(L0G, 1, 3), 256, 0, stream>>>(x, c, w0, b0, hA, 0);

        dim3 g3(NXR / 128, HD / 128, 3);
        {
            P3 b = {{Qbh + 0 * HD, Kbh + 0 * HD, Vbh + 0 * HD}};
            gemm_rs<1><<<g3, 256, 0, stream>>>(hA, wT + 0 * 3 * WTN, WTN, b, hB);
        }
        {
            P3 b = {{Qbh + 1 * HD, Kbh + 1 * HD, Vbh + 1 * HD}};
            gemm_rs<1><<<g3, 256, 0, stream>>>(hB, wT + 1 * 3 * WTN, WTN, b, hA);
        }
        {
            P3 b = {{Qbh + 2 * HD, Kbh + 2 * HD, Vbh + 2 * HD}};
            gemm_rs<1><<<g3, 256, 0, stream>>>(hA, wT + 2 * 3 * WTN, WTN, b, hB);
        }
        {
            P3 b = {{Qbo, Kbo, nullptr}};
            gemm_rs<0><<<dim3(NXR / 128, HD / 128, 2), 256, 0, stream>>>(
                hB, wT + 9 * WTN, WTN, b, hA);
        }
        vout_k<<<NCR / 4, 256, 0, stream>>>(hB + 2 * NET, VWo, Vbo, Vff);

        Qb = hA; Kb = hA + NET; Vf = Vff;
    } else {
        // ================= two-phase fallback (38.1 MB) =================
        u16*   R1 = (u16*)(ws + 6 * MB);
        u16*   R2 = (u16*)(ws + 22 * MB);
        float* Vff = (float*)(ws + 38 * MB);

        {
            P3 w0 = {{VW0, nullptr, nullptr}}, b0 = {{Vb0, nullptr, nullptr}};
            layer0_all<<<dim3(L0G, 1, 1), 256, 0, stream>>>(x, c, w0, b0, R1, 2);
        }
        dim3 gv(NXR / 128, HD / 128, 1);
        {
            P3 b = {{Vbh + 0 * HD, nullptr, nullptr}};
            gemm_rs<1><<<gv, 256, 0, stream>>>(R1, wT + (0 * 3 + 2) * WTN, 0, b, R2);
        }
        {
            P3 b = {{Vbh + 1 * HD, nullptr, nullptr}};
            gemm_rs<1><<<gv, 256, 0, stream>>>(R2, wT + (1 * 3 + 2) * WTN, 0, b, R1);
        }
        {
            P3 b = {{Vbh + 2 * HD, nullptr, nullptr}};
            gemm_rs<1><<<gv, 256, 0, stream>>>(R1, wT + (2 * 3 + 2) * WTN, 0, b, R2);
        }
        vout_k<<<NCR / 4, 256, 0, stream>>>(R2, VWo, Vbo, Vff);

        {
            P3 w0 = {{QW0, KW0, nullptr}}, b0 = {{Qb0, Kb0, nullptr}};
            layer0_all<<<dim3(L0G, 1, 2), 256, 0, stream>>>(x, c, w0, b0, R1, 0);
        }
        dim3 gqk(NXR / 128, HD / 128, 2);
        {
            P3 b = {{Qbh + 0 * HD, Kbh + 0 * HD, nullptr}};
            gemm_rs<1><<<gqk, 256, 0, stream>>>(R1, wT + 0 * 3 * WTN, WTN, b, R2);
        }
        {
            P3 b = {{Qbh + 1 * HD, Kbh + 1 * HD, nullptr}};
            gemm_rs<1><<<gqk, 256, 0, stream>>>(R2, wT + 1 * 3 * WTN, WTN, b, R1);
        }
        {
            P3 b = {{Qbh + 2 * HD, Kbh + 2 * HD, nullptr}};
            gemm_rs<1><<<gqk, 256, 0, stream>>>(R1, wT + 2 * 3 * WTN, WTN, b, R2);
        }
        {
            P3 b = {{Qbo, Kbo, nullptr}};
            gemm_rs<0><<<gqk, 256, 0, stream>>>(R2, wT + 9 * WTN, WTN, b, R1);
        }
        Qb = R1; Kb = R1 + NET; Vf = Vff;
    }

    // ---- attention ----
    hipMemsetAsync(d_out, 0, (size_t)out_size * sizeof(float), stream);
    attn_mfma<<<dim3(NSL, NXR / 128), 256, 0, stream>>>(Qb, Kb, Vf, (float*)d_out);
}